// Round 1
// baseline (406.744 us; speedup 1.0000x reference)
//
#include <hip/hip_runtime.h>

#define CD 128   // channels
#define KK 9     // 3x3 kernel taps

typedef __bf16 bf16x8 __attribute__((ext_vector_type(8)));
typedef float  f32x4  __attribute__((ext_vector_type(4)));
typedef float  f32x16 __attribute__((ext_vector_type(16)));

// ---------------------------------------------------------------------------
// Transpose + cast W[k][c][o] (f32) -> W_T[k][o][c] (bf16 bits). 18 blocks
// (2 weights x 9 taps), 128x128 tile via LDS. Tiny kernel (~0.6 MB total).
// ---------------------------------------------------------------------------
__global__ __launch_bounds__(256) void transpose_w(const float* __restrict__ W1,
                                                   const float* __restrict__ W2,
                                                   unsigned short* __restrict__ W1T,
                                                   unsigned short* __restrict__ W2T) {
    __shared__ unsigned short tile[128 * 129];
    const int b = blockIdx.x;            // 0..17
    const int k = (b < KK) ? b : b - KK;
    const float* src = ((b < KK) ? W1 : W2) + k * (CD * CD);
    unsigned short* dst = ((b < KK) ? W1T : W2T) + k * (CD * CD);
    #pragma unroll 4
    for (int p = 0; p < 64; ++p) {
        int idx = p * 256 + threadIdx.x;     // coalesced read W[k][c][o]
        int c = idx >> 7, o = idx & 127;
        __bf16 h = (__bf16)src[idx];
        tile[o * 129 + c] = __builtin_bit_cast(unsigned short, h);
    }
    __syncthreads();
    #pragma unroll 4
    for (int p = 0; p < 64; ++p) {
        int idx = p * 256 + threadIdx.x;     // coalesced write W_T[k][o][c]
        int o = idx >> 7, c = idx & 127;
        dst[idx] = tile[o * 129 + c];
    }
}

// ---------------------------------------------------------------------------
// Gather-GEMM submanifold conv. One wave = 64 sites (2 M-frags of 32) x 128
// out channels (4 N-frags of 32), mfma_f32_32x32x16_bf16, reduce over
// K*C = 1152 in 72 steps of 16.
//  AF32  : A gathered from f32 feats (converted in-register)  [conv1]
//          else from bf16 rows in workspace                    [conv2]
//  FIRST : epilogue relu -> bf16 hidden; else +residual, relu -> f32 out
// Sentinel neighbors (idx==n) are clamped to row 0 and cndmask'd to zero,
// so no pad row / memset is needed and results are bit-deterministic.
// ---------------------------------------------------------------------------
template <bool AF32, bool FIRST>
__global__ __launch_bounds__(256, 2) void conv_kernel(
    const float* __restrict__ feats,        // f32 A source (AF32) / residual
    const unsigned short* __restrict__ asrc,// bf16 A source (!AF32)
    const unsigned short* __restrict__ WT,  // bf16 W_T[k][o][c]
    const int* __restrict__ nbr,            // [n][9] neighbor row or n
    unsigned short* __restrict__ hout,      // bf16 out (FIRST)
    float* __restrict__ fout,               // f32 out (!FIRST)
    const int n)
{
    const int lane = threadIdx.x & 63;
    const int l31  = lane & 31;             // MFMA row (A) / col (B,C)
    const int kh   = lane >> 5;             // K-half within a step
    const int wave = threadIdx.x >> 6;
    const int base = blockIdx.x * 256 + wave * 64;
    const int s0 = base + l31;
    const int s1 = base + 32 + l31;
    const int sc0 = (s0 < n) ? s0 : (n - 1);
    const int sc1 = (s1 < n) ? s1 : (n - 1);

    f32x16 acc[2][4];
    #pragma unroll
    for (int m = 0; m < 2; ++m)
        #pragma unroll
        for (int nf = 0; nf < 4; ++nf)
            #pragma unroll
            for (int i = 0; i < 16; ++i) acc[m][nf][i] = 0.f;

    bf16x8 zed;
    #pragma unroll
    for (int e = 0; e < 8; ++e) zed[e] = (__bf16)0.f;

    #pragma unroll 1
    for (int k = 0; k < KK; ++k) {
        const int r0 = nbr[sc0 * KK + k];
        const int r1 = nbr[sc1 * KK + k];
        const bool v0 = (unsigned)r0 < (unsigned)n;   // idx==n => inactive
        const bool v1 = (unsigned)r1 < (unsigned)n;
        const size_t rr0 = (size_t)(v0 ? r0 : 0) * CD;
        const size_t rr1 = (size_t)(v1 ? r1 : 0) * CD;

        #pragma unroll
        for (int cs = 0; cs < 8; ++cs) {
            const int coff = cs * 16 + kh * 8;        // c for this lane's 8 elems
            bf16x8 a0, a1;
            if (AF32) {
                f32x4 lo0 = *(const f32x4*)(feats + rr0 + coff);
                f32x4 hi0 = *(const f32x4*)(feats + rr0 + coff + 4);
                f32x4 lo1 = *(const f32x4*)(feats + rr1 + coff);
                f32x4 hi1 = *(const f32x4*)(feats + rr1 + coff + 4);
                #pragma unroll
                for (int e = 0; e < 4; ++e) {
                    a0[e] = (__bf16)lo0[e]; a0[e + 4] = (__bf16)hi0[e];
                    a1[e] = (__bf16)lo1[e]; a1[e + 4] = (__bf16)hi1[e];
                }
            } else {
                a0 = *(const bf16x8*)(asrc + rr0 + coff);
                a1 = *(const bf16x8*)(asrc + rr1 + coff);
            }
            a0 = v0 ? a0 : zed;
            a1 = v1 ? a1 : zed;

            #pragma unroll
            for (int nf = 0; nf < 4; ++nf) {
                // B[k_local][o]: lane l31 = out channel col, kh*8+e = c
                bf16x8 b = *(const bf16x8*)(WT +
                    (size_t)((k * CD + nf * 32 + l31) * CD + coff));
                acc[0][nf] = __builtin_amdgcn_mfma_f32_32x32x16_bf16(a0, b, acc[0][nf], 0, 0, 0);
                acc[1][nf] = __builtin_amdgcn_mfma_f32_32x32x16_bf16(a1, b, acc[1][nf], 0, 0, 0);
            }
        }
    }

    // Epilogue: C/D map col=lane&31, row=(rg&3)+8*(rg>>2)+4*kh
    #pragma unroll
    for (int m = 0; m < 2; ++m) {
        #pragma unroll
        for (int rg = 0; rg < 16; ++rg) {
            const int row  = (rg & 3) + 8 * (rg >> 2) + 4 * kh;
            const int srow = base + m * 32 + row;
            if (srow < n) {
                #pragma unroll
                for (int nf = 0; nf < 4; ++nf) {
                    float v = acc[m][nf][rg];
                    const size_t oi = (size_t)srow * CD + nf * 32 + l31;
                    if (FIRST) {
                        v = v > 0.f ? v : 0.f;
                        hout[oi] = __builtin_bit_cast(unsigned short, (__bf16)v);
                    } else {
                        v += feats[oi];
                        v = v > 0.f ? v : 0.f;
                        fout[oi] = v;
                    }
                }
            }
        }
    }
}

extern "C" void kernel_launch(void* const* d_in, const int* in_sizes, int n_in,
                              void* d_out, int out_size, void* d_ws, size_t ws_size,
                              hipStream_t stream) {
    const float* feats = (const float*)d_in[0];
    const int*   nbr   = (const int*)d_in[1];
    const float* W1    = (const float*)d_in[2];
    const float* W2    = (const float*)d_in[3];
    float* out = (float*)d_out;

    const int n = in_sizes[0] / CD;   // active sites (200000)

    // workspace: hidden bf16 [n][128], then W1T, W2T (bf16). ~51.8 MB total.
    unsigned short* hid = (unsigned short*)d_ws;
    unsigned short* W1T = hid + (size_t)n * CD;
    unsigned short* W2T = W1T + KK * CD * CD;

    transpose_w<<<2 * KK, 256, 0, stream>>>(W1, W2, W1T, W2T);

    const int grid = (n + 255) / 256;
    conv_kernel<true,  true ><<<grid, 256, 0, stream>>>(feats, nullptr, W1T, nbr, hid, nullptr, n);
    conv_kernel<false, false><<<grid, 256, 0, stream>>>(feats, hid,     W2T, nbr, nullptr, out, n);
}

// Round 2
// 296.398 us; speedup vs baseline: 1.3723x; 1.3723x over previous
//
#include <hip/hip_runtime.h>

#define CD 128   // channels
#define KK 9     // 3x3 kernel taps

typedef __bf16 bf16x8 __attribute__((ext_vector_type(8)));
typedef float  f32x4  __attribute__((ext_vector_type(4)));
typedef float  f32x16 __attribute__((ext_vector_type(16)));

typedef __attribute__((address_space(1))) const void* gas_ptr;
typedef __attribute__((address_space(3))) void*       las_ptr;

// ---------------------------------------------------------------------------
// Transpose + cast W[k][c][o] (f32) -> W_T[k][o][c] (bf16 bits), linear layout.
// ---------------------------------------------------------------------------
__global__ __launch_bounds__(256) void transpose_w(const float* __restrict__ W1,
                                                   const float* __restrict__ W2,
                                                   unsigned short* __restrict__ W1T,
                                                   unsigned short* __restrict__ W2T) {
    __shared__ unsigned short tile[128 * 129];
    const int b = blockIdx.x;            // 0..17
    const int k = (b < KK) ? b : b - KK;
    const float* src = ((b < KK) ? W1 : W2) + k * (CD * CD);
    unsigned short* dst = ((b < KK) ? W1T : W2T) + k * (CD * CD);
    #pragma unroll 4
    for (int p = 0; p < 64; ++p) {
        int idx = p * 256 + threadIdx.x;     // coalesced read W[k][c][o]
        int c = idx >> 7, o = idx & 127;
        __bf16 h = (__bf16)src[idx];
        tile[o * 129 + c] = __builtin_bit_cast(unsigned short, h);
    }
    __syncthreads();
    #pragma unroll 4
    for (int p = 0; p < 64; ++p) {
        int idx = p * 256 + threadIdx.x;     // coalesced write W_T[k][o][c]
        int o = idx >> 7, c = idx & 127;
        dst[idx] = tile[o * 129 + c];
    }
}

// ---------------------------------------------------------------------------
// Gather-GEMM submanifold conv, latency-optimized:
//  - nbr indices prefetched one tap ahead
//  - weights double-buffered in LDS (2x32KB) via global_load_lds w=16,
//    XOR-swizzled on the GLOBAL SOURCE address (LDS dest stays linear),
//    read back with the same XOR -> ~4-way (b128 minimum) bank pattern
//  - per tap: A-gather phase (all loads issued up front) then MFMA phase
// One wave = 64 sites x 128 out channels, mfma_f32_32x32x16_bf16.
// ---------------------------------------------------------------------------
template <bool AF32, bool FIRST>
__global__ __launch_bounds__(256, 2) void conv_kernel(
    const float* __restrict__ feats,        // f32 A source (AF32) / residual
    const unsigned short* __restrict__ asrc,// bf16 A source (!AF32)
    const unsigned short* __restrict__ WT,  // bf16 W_T[k][o][c] linear
    const int* __restrict__ nbr,            // [n][9] neighbor row or n
    unsigned short* __restrict__ hout,      // bf16 out (FIRST)
    float* __restrict__ fout,               // f32 out (!FIRST)
    const int n)
{
    __shared__ char wbuf[2][32768];

    const int tid  = threadIdx.x;
    const int lane = tid & 63;
    const int l31  = lane & 31;             // MFMA row (A) / col (B,C)
    const int kh   = lane >> 5;             // K-half within a step
    const int wave = tid >> 6;
    const int base = blockIdx.x * 256 + wave * 64;
    const int s0 = base + l31;
    const int s1 = base + 32 + l31;
    const int sc0 = (s0 < n) ? s0 : (n - 1);
    const int sc1 = (s1 < n) ? s1 : (n - 1);

    // stage tap k's 32KB of W_T into wbuf[b]; linear LDS dest, swizzled src
    auto stage = [&](int b, int k) {
        const char* tap = (const char*)(WT + (size_t)k * CD * CD);
        char* lb = &wbuf[b][0];
        #pragma unroll
        for (int i = 0; i < 8; ++i) {
            const int chunk = (i * 4 + wave) * 1024;      // wave-uniform
            const int d = chunk + lane * 16;              // this lane's dest
            const int s = d ^ (((d >> 8) & 7) << 4);      // involution swizzle
            __builtin_amdgcn_global_load_lds((gas_ptr)(tap + s),
                                             (las_ptr)(lb + chunk), 16, 0, 0);
        }
    };

    f32x16 acc[2][4];
    #pragma unroll
    for (int m = 0; m < 2; ++m)
        #pragma unroll
        for (int nf = 0; nf < 4; ++nf)
            #pragma unroll
            for (int i = 0; i < 16; ++i) acc[m][nf][i] = 0.f;

    bf16x8 zed;
    #pragma unroll
    for (int e = 0; e < 8; ++e) zed[e] = (__bf16)0.f;

    // prologue: idx for tap 0, stage tap 0
    int c0 = nbr[(size_t)sc0 * KK];
    int c1 = nbr[(size_t)sc1 * KK];
    stage(0, 0);
    __syncthreads();

    const int swq = (l31 & 7) << 4;   // read-side XOR (== (row&7)<<4)

    #pragma unroll 1
    for (int k = 0; k < KK; ++k) {
        int n0 = 0, n1 = 0;
        if (k + 1 < KK) {
            n0 = nbr[(size_t)sc0 * KK + k + 1];       // prefetch next indices
            n1 = nbr[(size_t)sc1 * KK + k + 1];
            stage((k + 1) & 1, k + 1);                // prefetch next weights
        }

        const bool v0 = (unsigned)c0 < (unsigned)n;   // idx==n => inactive
        const bool v1 = (unsigned)c1 < (unsigned)n;
        const size_t rr0 = (size_t)(v0 ? c0 : 0) * CD;
        const size_t rr1 = (size_t)(v1 ? c1 : 0) * CD;

        // ---- A phase: issue all gathers for this tap, convert/select ----
        bf16x8 a0[8], a1[8];
        if (AF32) {
            #pragma unroll
            for (int cs = 0; cs < 8; ++cs) {
                const int coff = cs * 16 + kh * 8;
                f32x4 lo0 = *(const f32x4*)(feats + rr0 + coff);
                f32x4 hi0 = *(const f32x4*)(feats + rr0 + coff + 4);
                f32x4 lo1 = *(const f32x4*)(feats + rr1 + coff);
                f32x4 hi1 = *(const f32x4*)(feats + rr1 + coff + 4);
                #pragma unroll
                for (int e = 0; e < 4; ++e) {
                    a0[cs][e] = (__bf16)lo0[e]; a0[cs][e + 4] = (__bf16)hi0[e];
                    a1[cs][e] = (__bf16)lo1[e]; a1[cs][e + 4] = (__bf16)hi1[e];
                }
                a0[cs] = v0 ? a0[cs] : zed;
                a1[cs] = v1 ? a1[cs] : zed;
            }
        } else {
            #pragma unroll
            for (int cs = 0; cs < 8; ++cs) {
                const int coff = cs * 16 + kh * 8;
                a0[cs] = *(const bf16x8*)(asrc + rr0 + coff);
                a1[cs] = *(const bf16x8*)(asrc + rr1 + coff);
                a0[cs] = v0 ? a0[cs] : zed;
                a1[cs] = v1 ? a1[cs] : zed;
            }
        }

        // ---- MFMA phase: B from LDS (swizzled), 64 MFMAs ----
        const char* wb = &wbuf[k & 1][0];
        #pragma unroll
        for (int cs = 0; cs < 8; ++cs) {
            #pragma unroll
            for (int nf = 0; nf < 4; ++nf) {
                const int x = ((nf * 32 + l31) << 8) + (cs << 5) + (kh << 4);
                bf16x8 b = *(const bf16x8*)(wb + (x ^ swq));
                acc[0][nf] = __builtin_amdgcn_mfma_f32_32x32x16_bf16(a0[cs], b, acc[0][nf], 0, 0, 0);
                acc[1][nf] = __builtin_amdgcn_mfma_f32_32x32x16_bf16(a1[cs], b, acc[1][nf], 0, 0, 0);
            }
        }

        __syncthreads();   // drains stage(k+1) (issued ~700cy ago) + LDS reads
        c0 = n0; c1 = n1;
    }

    // Epilogue: C/D map col=lane&31, row=(rg&3)+8*(rg>>2)+4*kh
    #pragma unroll
    for (int m = 0; m < 2; ++m) {
        #pragma unroll
        for (int rg = 0; rg < 16; ++rg) {
            const int row  = (rg & 3) + 8 * (rg >> 2) + 4 * kh;
            const int srow = base + m * 32 + row;
            if (srow < n) {
                #pragma unroll
                for (int nf = 0; nf < 4; ++nf) {
                    float v = acc[m][nf][rg];
                    const size_t oi = (size_t)srow * CD + nf * 32 + l31;
                    if (FIRST) {
                        v = v > 0.f ? v : 0.f;
                        hout[oi] = __builtin_bit_cast(unsigned short, (__bf16)v);
                    } else {
                        v += feats[oi];
                        v = v > 0.f ? v : 0.f;
                        fout[oi] = v;
                    }
                }
            }
        }
    }
}

extern "C" void kernel_launch(void* const* d_in, const int* in_sizes, int n_in,
                              void* d_out, int out_size, void* d_ws, size_t ws_size,
                              hipStream_t stream) {
    const float* feats = (const float*)d_in[0];
    const int*   nbr   = (const int*)d_in[1];
    const float* W1    = (const float*)d_in[2];
    const float* W2    = (const float*)d_in[3];
    float* out = (float*)d_out;

    const int n = in_sizes[0] / CD;   // active sites (200000)

    // workspace: hidden bf16 [n][128], then W1T, W2T (bf16). ~51.8 MB total.
    unsigned short* hid = (unsigned short*)d_ws;
    unsigned short* W1T = hid + (size_t)n * CD;
    unsigned short* W2T = W1T + KK * CD * CD;

    transpose_w<<<2 * KK, 256, 0, stream>>>(W1, W2, W1T, W2T);

    const int grid = (n + 255) / 256;
    conv_kernel<true,  true ><<<grid, 256, 0, stream>>>(feats, nullptr, W1T, nbr, hid, nullptr, n);
    conv_kernel<false, false><<<grid, 256, 0, stream>>>(feats, hid,     W2T, nbr, nullptr, out, n);
}